// Round 3
// baseline (3023.526 us; speedup 1.0000x reference)
//
#include <hip/hip_runtime.h>

#define T_ 25
#define V_ 10000
#define NWG_ 192

typedef short bf16x8 __attribute__((ext_vector_type(8)));
typedef float f32x4 __attribute__((ext_vector_type(4)));

__device__ __forceinline__ short f2bf(float x) {
  union { float f; unsigned u; } v; v.f = x;
  unsigned r = (v.u + 0x7fffu + ((v.u >> 16) & 1u)) >> 16;
  return (short)r;
}
__device__ __forceinline__ float sigm(float z) { return 1.f / (1.f + __expf(-z)); }
__device__ __forceinline__ float tanhfast(float z) {
  float e = __expf(2.f * z);
  return 1.f - 2.f / (e + 1.f);
}

__device__ __forceinline__ void gload_lds16(const void* g, void* l) {
  __builtin_amdgcn_global_load_lds((const __attribute__((address_space(1))) void*)g,
                                   (__attribute__((address_space(3))) void*)l, 16, 0, 0);
}

// MFMA-A-fragment-linear layout: value (row, col) lives at
// blk = (col>>5)*8 + (row>>4); lane = (row&15) | (((col>>3)&3)<<4); elem = col&7
__device__ __forceinline__ int FL(int row, int col) {
  return (((col >> 5) * 8 + (row >> 4)) << 9) | (((row & 15) | (((col >> 3) & 3) << 4)) << 3) | (col & 7);
}

// ---------------- device-scope grid barrier (all NWG_ WGs co-resident) ----------------
__device__ __forceinline__ void gbar(int* bar, int g) {
  __syncthreads();
  if (threadIdx.x == 0) {
    __threadfence();
    int prev = __hip_atomic_fetch_add(&bar[0], 1, __ATOMIC_ACQ_REL, __HIP_MEMORY_SCOPE_AGENT);
    if (prev == NWG_ - 1) {
      __hip_atomic_store(&bar[0], 0, __ATOMIC_RELAXED, __HIP_MEMORY_SCOPE_AGENT);
      __hip_atomic_store(&bar[1], g, __ATOMIC_RELEASE, __HIP_MEMORY_SCOPE_AGENT);
    } else {
      while (__hip_atomic_load(&bar[1], __ATOMIC_ACQUIRE, __HIP_MEMORY_SCOPE_AGENT) < g)
        __builtin_amdgcn_s_sleep(2);
    }
    __threadfence();
  }
  __syncthreads();
}

// ---------------- merged transpose + cast f32[R,C] -> bf16[C,R] ----------------
struct TJob { const float* src; short* dst; int R, C, t0; };
struct TJobs { TJob j[10]; };

__global__ void tcast_all(TJobs J) {
  __shared__ float t[32][33];
  int bid = blockIdx.x;
  int ji = 0;
  while (ji < 9 && bid >= J.j[ji + 1].t0) ji++;
  const float* src = J.j[ji].src;
  short* dst = J.j[ji].dst;
  int R = J.j[ji].R, C = J.j[ji].C;
  int rel = bid - J.j[ji].t0;
  int ctiles = (C + 31) >> 5;
  int rt0 = (rel / ctiles) * 32, ct0 = (rel % ctiles) * 32;
  int tx = threadIdx.x, ty = threadIdx.y; // 32x8
#pragma unroll
  for (int i = 0; i < 4; i++) {
    int r = rt0 + ty + i * 8, c = ct0 + tx;
    if (r < R && c < C) t[ty + i * 8][tx] = src[(size_t)r * C + c];
  }
  __syncthreads();
#pragma unroll
  for (int i = 0; i < 4; i++) {
    int c = ct0 + ty + i * 8, r = rt0 + tx;
    if (r < R && c < C) dst[(size_t)c * R + r] = f2bf(t[tx][ty + i * 8]);
  }
}

// ---------------- build X0 [T*B, 1024] bf16 : [emb(tok) | cnn] ----------------
__global__ void build_x0(const int* __restrict__ tok, const float* __restrict__ emb,
                         const float* __restrict__ cnn, short* __restrict__ X0) {
  int row = blockIdx.x;           // t*128 + b
  int t = row >> 7, b = row & 127;
  int tk = tok[b * T_ + t];
  const float* er = emb + (size_t)tk * 512;
  short* dst = X0 + (size_t)row * 1024;
  for (int i = threadIdx.x; i < 1024; i += 256)
    dst[i] = f2bf(i < 512 ? er[i] : cnn[b * 512 + (i - 512)]);
}

// ---------------- init hidden state (xh1b in FL layout) ----------------
__global__ void init_h(const float* __restrict__ ihs, float* h0f, float* h1f, short* xh1b) {
  int i = blockIdx.x * 256 + threadIdx.x;  // 0 .. 65535, i = b*512 + h
  if (i < 65536) {
    int b = i >> 9, h = i & 511;
    float v0 = ihs[i], v1 = ihs[65536 + i];
    h0f[i] = v0; h1f[i] = v1;
    xh1b[FL(b, h)] = f2bf(v0);
    xh1b[FL(b, 512 + h)] = f2bf(v1);
  }
}

__global__ void write_final(const float* __restrict__ h0f, const float* __restrict__ h1f,
                            float* __restrict__ out) {
  int i = blockIdx.x * 256 + threadIdx.x;
  if (i < 65536) {
    out[32000000 + i] = h0f[i];
    out[32000000 + 65536 + i] = h1f[i];
  }
}

// ---------------- persistent recurrence kernel ----------------
struct RP {
  short *xh1b, *rh0b, *xc1b0, *xc1b1, *H1all;
  float *u0f, *u1f, *h0f, *h1f;
  const float *A0;
  const short *Whur0T, *Whc0T, *W1urT, *Wc1T;
  const float *bu1, *br1, *bc1;
  int *bar;
};

template<int NKS>
__device__ __forceinline__ void wload(const short* __restrict__ Wt, int n0, int lane, bf16x8* wfr) {
  const short* p = Wt + (size_t)(n0 + (lane & 15)) * (NKS * 32) + ((lane >> 4) * 8);
#pragma unroll
  for (int ks = 0; ks < NKS; ks++) wfr[ks] = *(const bf16x8*)(p + (size_t)ks * 32);
}

template<int NKS>
__device__ __forceinline__ void kcompute(const short* __restrict__ A, int rb0, int lane,
                                         const bf16x8* __restrict__ wfr, f32x4* acc) {
  const short* ap = A + rb0 * 512 + lane * 8;
#pragma unroll
  for (int ks = 0; ks < NKS; ks++) {
    bf16x8 a0 = *(const bf16x8*)(ap + ks * 4096);
    bf16x8 a1 = *(const bf16x8*)(ap + ks * 4096 + 512);
    acc[ks & 1]       = __builtin_amdgcn_mfma_f32_16x16x32_bf16(a0, wfr[ks], acc[ks & 1], 0, 0, 0);
    acc[2 + (ks & 1)] = __builtin_amdgcn_mfma_f32_16x16x32_bf16(a1, wfr[ks], acc[2 + (ks & 1)], 0, 0, 0);
    if ((ks & 7) == 7) asm volatile("" ::: "memory");   // cap load-hoisting window
  }
}

__global__ __launch_bounds__(256) void recurrence(RP p) {
  const int role = blockIdx.x;
  const int tid = threadIdx.x, wv = tid >> 6, lane = tid & 63;
  const int lr = lane & 15, lg = lane >> 4;
  int gen = 0;

  if (role < 64) {
    // ---- P3: layer-1 u,r gates. out[128,1024], K=1024, A=xh1b ----
    const int nt = role >> 1, mh = role & 1;
    const int colb = nt * 32 + (wv & 1) * 16;
    const int rb0 = (mh * 64 + (wv >> 1) * 32) >> 4;
    bf16x8 wfr[32]; wload<32>(p.W1urT, colb, lane, wfr);
    gbar(p.bar, ++gen); gbar(p.bar, ++gen);
    for (int t = 0; t < T_; t++) {
      f32x4 acc[4] = {};
      kcompute<32>(p.xh1b, rb0, lane, wfr, acc);
      f32x4 am[2] = { acc[0] + acc[1], acc[2] + acc[3] };
      short* xc = (t & 1) ? p.xc1b1 : p.xc1b0;
#pragma unroll
      for (int m = 0; m < 2; m++)
#pragma unroll
        for (int i = 0; i < 4; i++) {
          int row = (rb0 + m) * 16 + lg * 4 + i;
          int col = colb + lr;
          float z = am[m][i] + (col < 512 ? p.bu1[col] : p.br1[col - 512]);
          float s = sigm(z);
          if (col < 512) p.u1f[row * 512 + col] = s;
          else xc[FL(row, col)] = f2bf(s * p.h1f[row * 512 + (col - 512)]);
        }
      gbar(p.bar, ++gen);   // end alpha(t)
      gbar(p.bar, ++gen);   // end beta(t) (idle)
    }
  } else if (role < 128) {
    // ---- P1: layer-0 u,r gates for step t+1. out[128,1024], K=512, A=xh1b[:,:512] ----
    const int r2 = role - 64;
    const int nt = r2 >> 1, mh = r2 & 1;
    const int colb = nt * 32 + (wv & 1) * 16;
    const int rb0 = (mh * 64 + (wv >> 1) * 32) >> 4;
    bf16x8 wfr[16]; wload<16>(p.Whur0T, colb, lane, wfr);
    auto doP1 = [&](int tt) {
      f32x4 acc[4] = {};
      kcompute<16>(p.xh1b, rb0, lane, wfr, acc);
      f32x4 am[2] = { acc[0] + acc[1], acc[2] + acc[3] };
      const float* a0s = p.A0 + (size_t)tt * 196608;
#pragma unroll
      for (int m = 0; m < 2; m++)
#pragma unroll
        for (int i = 0; i < 4; i++) {
          int row = (rb0 + m) * 16 + lg * 4 + i;
          int col = colb + lr;
          float z = am[m][i] + a0s[row * 1536 + col];
          float s = sigm(z);
          if (col < 512) p.u0f[row * 512 + col] = s;
          else p.rh0b[FL(row, col - 512)] = f2bf(s * p.h0f[row * 512 + (col - 512)]);
        }
    };
    doP1(0);
    gbar(p.bar, ++gen); gbar(p.bar, ++gen);
    for (int t = 0; t < T_; t++) {
      if (t < T_ - 1) doP1(t + 1);
      gbar(p.bar, ++gen);
      gbar(p.bar, ++gen);
    }
  } else if (role < 160) {
    // ---- P4: layer-1 cand + h1 update. out[128,512], K=1024, A=xc1b[t&1] ----
    const int r4 = role - 128;
    const int nt = r4 >> 1, mh = r4 & 1;
    const int colb = nt * 32 + (wv & 1) * 16;
    const int rb0 = (mh * 64 + (wv >> 1) * 32) >> 4;
    bf16x8 wfr[32]; wload<32>(p.Wc1T, colb, lane, wfr);
    gbar(p.bar, ++gen); gbar(p.bar, ++gen);
    for (int t = 0; t < T_; t++) {
      gbar(p.bar, ++gen);   // alpha idle
      const short* xc = (t & 1) ? p.xc1b1 : p.xc1b0;
      f32x4 acc[4] = {};
      kcompute<32>(xc, rb0, lane, wfr, acc);
      f32x4 am[2] = { acc[0] + acc[1], acc[2] + acc[3] };
#pragma unroll
      for (int m = 0; m < 2; m++)
#pragma unroll
        for (int i = 0; i < 4; i++) {
          int row = (rb0 + m) * 16 + lg * 4 + i;
          int col = colb + lr;
          float z = am[m][i] + p.bc1[col];
          float cc = tanhfast(z);
          float u = p.u1f[row * 512 + col], h = p.h1f[row * 512 + col];
          float hn = u * h + (1.f - u) * cc;
          p.h1f[row * 512 + col] = hn;
          short hb = f2bf(hn);
          p.xh1b[FL(row, 512 + col)] = hb;
          p.H1all[(size_t)t * 65536 + row * 512 + col] = hb;
        }
      gbar(p.bar, ++gen);   // end beta(t)
    }
  } else {
    // ---- P2: layer-0 cand + h0 update for step t+1. out[128,512], K=512, A=rh0b ----
    const int r2 = role - 160;
    const int nt = r2 >> 1, mh = r2 & 1;
    const int colb = nt * 32 + (wv & 1) * 16;
    const int rb0 = (mh * 64 + (wv >> 1) * 32) >> 4;
    bf16x8 wfr[16]; wload<16>(p.Whc0T, colb, lane, wfr);
    auto doP2 = [&](int tt) {
      f32x4 acc[4] = {};
      kcompute<16>(p.rh0b, rb0, lane, wfr, acc);
      f32x4 am[2] = { acc[0] + acc[1], acc[2] + acc[3] };
      const float* a0s = p.A0 + (size_t)tt * 196608;
      short* xc = (tt & 1) ? p.xc1b1 : p.xc1b0;
#pragma unroll
      for (int m = 0; m < 2; m++)
#pragma unroll
        for (int i = 0; i < 4; i++) {
          int row = (rb0 + m) * 16 + lg * 4 + i;
          int col = colb + lr;
          float z = am[m][i] + a0s[row * 1536 + 1024 + col];
          float c = tanhfast(z);
          float u = p.u0f[row * 512 + col], h = p.h0f[row * 512 + col];
          float hn = u * h + (1.f - u) * c;
          p.h0f[row * 512 + col] = hn;
          short hb = f2bf(hn);
          p.xh1b[FL(row, col)] = hb;
          xc[FL(row, col)] = hb;
        }
    };
    gbar(p.bar, ++gen);
    doP2(0);
    gbar(p.bar, ++gen);
    for (int t = 0; t < T_; t++) {
      gbar(p.bar, ++gen);   // alpha idle
      if (t < T_ - 1) doP2(t + 1);
      gbar(p.bar, ++gen);
    }
  }
}

// ---------------- big MFMA GEMM (A0 precompute + logits) ----------------
struct GP {
  const short* A; const short* Bt;
  int lda, ldb, N, K;
  const float* bias0; const float* bias1; const float* bias2;
  float* fdst;
  float* outp; const float* bout;
};

template<int BM, int BN, int VAR>
__device__ __forceinline__ void gemm_core(const GP& p, short* la, short* lb, int bm, int bn, short* smem) {
  const int tid = threadIdx.x;
  const int wave = tid >> 6, lane = tid & 63;
  const int wm = wave >> 1, wn = wave & 1;
  constexpr int WM = BM / 2, WN = BN / 2;
  constexpr int MF = WM / 16, NF = WN / 16;
  const int lr = lane & 15, lg = lane >> 4;
  const short* Abase = p.A + (size_t)bm * BM * p.lda;
  const short* Bbase = p.Bt + (size_t)bn * BN * p.ldb;
  const int bnmax = p.N - bn * BN;
  f32x4 acc[MF][NF] = {};
  const int nkb = p.K >> 6;

  auto stA = [&](int buf, int k0) {
    constexpr int NI = BM / 32;
#pragma unroll
    for (int j = 0; j < NI; j++) {
      int glin = j * 256 + tid;
      int row = glin >> 3, gc = glin & 7;
      int gcs = gc ^ (row & 7);
      gload_lds16(Abase + (size_t)row * p.lda + k0 + gcs * 8,
                  &la[buf * BM * 64 + j * 2048 + wave * 512]);
    }
  };
  auto stB = [&](int buf, int k0) {
    constexpr int NI = BN / 32;
#pragma unroll
    for (int j = 0; j < NI; j++) {
      int glin = j * 256 + tid;
      int row = glin >> 3, gc = glin & 7;
      int gcs = gc ^ (row & 7);
      int rc = row < bnmax ? row : bnmax - 1;
      gload_lds16(Bbase + (size_t)rc * p.ldb + k0 + gcs * 8,
                  &lb[buf * BN * 64 + j * 2048 + wave * 512]);
    }
  };

  stA(0, 0); stB(0, 0);
  __syncthreads();
  int buf = 0;
  for (int kb = 0; kb < nkb; kb++) {
    if (kb + 1 < nkb) { stA(buf ^ 1, (kb + 1) * 64); stB(buf ^ 1, (kb + 1) * 64); }
    bf16x8 af[2][MF], bfr[2][NF];
#pragma unroll
    for (int ks = 0; ks < 2; ks++) {
#pragma unroll
      for (int m = 0; m < MF; m++) {
        int ar = wm * WM + m * 16 + lr;
        af[ks][m] = *(const bf16x8*)&la[buf * BM * 64 + (ar * 8 + ((ks * 4 + lg) ^ (ar & 7))) * 8];
      }
#pragma unroll
      for (int n = 0; n < NF; n++) {
        int br = wn * WN + n * 16 + lr;
        bfr[ks][n] = *(const bf16x8*)&lb[buf * BN * 64 + (br * 8 + ((ks * 4 + lg) ^ (br & 7))) * 8];
      }
    }
#pragma unroll
    for (int ks = 0; ks < 2; ks++)
#pragma unroll
      for (int m = 0; m < MF; m++)
#pragma unroll
        for (int n = 0; n < NF; n++)
          acc[m][n] = __builtin_amdgcn_mfma_f32_16x16x32_bf16(af[ks][m], bfr[ks][n], acc[m][n], 0, 0, 0);
    __syncthreads();
    buf ^= 1;
  }

  if constexpr (VAR == 0) {            // A0 = x@Wx + bias (3 gates), f32 row-major out
#pragma unroll
    for (int m = 0; m < MF; m++)
#pragma unroll
      for (int n = 0; n < NF; n++)
#pragma unroll
        for (int i = 0; i < 4; i++) {
          int row = bm * BM + wm * WM + m * 16 + lg * 4 + i;
          int col = bn * BN + wn * WN + n * 16 + lr;
          if (col >= p.N) continue;
          float bias = col < 512 ? p.bias0[col] : (col < 1024 ? p.bias1[col - 512] : p.bias2[col - 1024]);
          p.fdst[(size_t)row * 1536 + col] = acc[m][n][i] + bias;
        }
  } else {                             // VAR 5: logits -> smem transpose -> float4 full-line stores
    float* fs = (float*)smem;          // 128x128 f32 = 64 KiB
#pragma unroll
    for (int m = 0; m < MF; m++)
#pragma unroll
      for (int n = 0; n < NF; n++)
#pragma unroll
        for (int i = 0; i < 4; i++) {
          int lrow = wm * WM + m * 16 + lg * 4 + i;
          int lcol = wn * WN + n * 16 + lr;
          int col = bn * BN + lcol;
          fs[lrow * 128 + lcol] = acc[m][n][i] + (col < p.N ? p.bout[col] : 0.f);
        }
    __syncthreads();
#pragma unroll
    for (int j = 0; j < 16; j++) {
      int idx = j * 256 + tid;         // 0..4095 float4 slots
      int r = idx >> 5, c4 = (idx & 31) << 2;
      int gr = bm * BM + r;
      int tt = gr >> 7, b = gr & 127;
      int col = bn * BN + c4;
      if (col < p.N) {
        f32x4 v = *(const f32x4*)&fs[r * 128 + c4];
        *(f32x4*)&p.outp[((size_t)b * T_ + tt) * V_ + col] = v;
      }
    }
  }
}

template<int BM, int BN, int VAR>
__global__ __launch_bounds__(256) void gemm_one(GP p) {
  __shared__ short smem[2 * BM * 64 + 2 * BN * 64];
  int bm, bn;
  if constexpr (VAR == 5) {
    int lin = blockIdx.y * gridDim.x + blockIdx.x;     // 0..1974
    const int nwg = 79 * 25, q = nwg / 8, r8 = nwg % 8;
    int xcd = lin % 8, idx = lin / 8;
    int nlin = (xcd < r8 ? xcd * (q + 1) : r8 * (q + 1) + (xcd - r8) * q) + idx;
    bm = nlin % 25; bn = nlin / 25;                    // bn-major chunks per XCD
  } else { bm = blockIdx.y; bn = blockIdx.x; }
  gemm_core<BM, BN, VAR>(p, smem, smem + 2 * BM * 64, bm, bn, smem);
}

// ---------------- host ----------------
extern "C" void kernel_launch(void* const* d_in, const int* in_sizes, int n_in,
                              void* d_out, int out_size, void* d_ws, size_t ws_size,
                              hipStream_t stream) {
  const int*   tokens = (const int*)  d_in[0];
  const float* cnn    = (const float*)d_in[1];
  const float* ihs    = (const float*)d_in[2];
  const float* emb    = (const float*)d_in[3];
  const float* Wu0 = (const float*)d_in[4];
  const float* Wr0 = (const float*)d_in[5];
  const float* Wc0 = (const float*)d_in[6];
  const float* bu0 = (const float*)d_in[7];
  const float* br0 = (const float*)d_in[8];
  const float* bc0 = (const float*)d_in[9];
  const float* Wu1 = (const float*)d_in[10];
  const float* Wr1 = (const float*)d_in[11];
  const float* Wc1 = (const float*)d_in[12];
  const float* bu1 = (const float*)d_in[13];
  const float* br1 = (const float*)d_in[14];
  const float* bc1 = (const float*)d_in[15];
  const float* Wout = (const float*)d_in[16];
  const float* bout = (const float*)d_in[17];
  float* out = (float*)d_out;

  char* w = (char*)d_ws;
  size_t off = 0;
  auto alloc = [&](size_t bytes) { void* p = w + off; off += (bytes + 255) & ~255ull; return p; };
  short* WxT    = (short*)alloc(1536 * 1024 * 2);
  short* Whur0T = (short*)alloc(1024 * 512 * 2);
  short* Whc0T  = (short*)alloc(512 * 512 * 2);
  short* W1urT  = (short*)alloc(1024 * 1024 * 2);
  short* Wc1T   = (short*)alloc(512 * 1024 * 2);
  short* WoutT  = (short*)alloc((size_t)10000 * 512 * 2);
  short* X0     = (short*)alloc((size_t)3200 * 1024 * 2);
  float* A0     = (float*)alloc((size_t)3200 * 1536 * 4);
  short* H1all  = (short*)alloc((size_t)3200 * 512 * 2);
  float* u0f    = (float*)alloc(128 * 512 * 4);
  float* u1f    = (float*)alloc(128 * 512 * 4);
  float* h0f    = (float*)alloc(128 * 512 * 4);
  float* h1f    = (float*)alloc(128 * 512 * 4);
  short* rh0b   = (short*)alloc(128 * 512 * 2);
  short* xh1b   = (short*)alloc(128 * 1024 * 2);
  short* xc1b0  = (short*)alloc(128 * 1024 * 2);
  short* xc1b1  = (short*)alloc(128 * 1024 * 2);
  int*   bar    = (int*)alloc(256);
  (void)ws_size; (void)in_sizes; (void)n_in; (void)out_size;

  {
    TJobs J;
    J.j[0] = { Wu0,              WxT,                1024, 512,  0    };
    J.j[1] = { Wr0,              WxT + 512 * 1024,   1024, 512,  512  };
    J.j[2] = { Wc0,              WxT + 1024 * 1024,  1024, 512,  1024 };
    J.j[3] = { Wu0 + 1024 * 512, Whur0T,             512,  512,  1536 };
    J.j[4] = { Wr0 + 1024 * 512, Whur0T + 512 * 512, 512,  512,  1792 };
    J.j[5] = { Wc0 + 1024 * 512, Whc0T,              512,  512,  2048 };
    J.j[6] = { Wu1,              W1urT,              1024, 512,  2304 };
    J.j[7] = { Wr1,              W1urT + 512 * 1024, 1024, 512,  2816 };
    J.j[8] = { Wc1,              Wc1T,               1024, 512,  3328 };
    J.j[9] = { Wout,             WoutT,              512,  10000, 3840 };
    tcast_all<<<8848, dim3(32, 8), 0, stream>>>(J);
  }

  build_x0<<<3200, 256, 0, stream>>>(tokens, emb, cnn, X0);
  init_h<<<256, 256, 0, stream>>>(ihs, h0f, h1f, xh1b);
  hipMemsetAsync(bar, 0, 256, stream);

  // A0 = X0 @ WxT^T + biases : [3200,1536] f32
  {
    GP g = {};
    g.A = X0; g.lda = 1024; g.Bt = WxT; g.ldb = 1024; g.N = 1536; g.K = 1024;
    g.bias0 = bu0; g.bias1 = br0; g.bias2 = bc0; g.fdst = A0;
    gemm_one<128, 128, 0><<<dim3(12, 25), 256, 0, stream>>>(g);
  }

  // persistent recurrence: 52 barrier-phases, weights in registers
  {
    RP r = {};
    r.xh1b = xh1b; r.rh0b = rh0b; r.xc1b0 = xc1b0; r.xc1b1 = xc1b1; r.H1all = H1all;
    r.u0f = u0f; r.u1f = u1f; r.h0f = h0f; r.h1f = h1f;
    r.A0 = A0;
    r.Whur0T = Whur0T; r.Whc0T = Whc0T; r.W1urT = W1urT; r.Wc1T = Wc1T;
    r.bu1 = bu1; r.br1 = br1; r.bc1 = bc1;
    r.bar = bar;
    recurrence<<<dim3(NWG_), 256, 0, stream>>>(r);
  }

  // logits = H1all @ WoutT^T + bout -> out[b,t,v]
  {
    GP g = {};
    g.A = H1all; g.lda = 512; g.Bt = WoutT; g.ldb = 512; g.N = 10000; g.K = 512;
    g.outp = out; g.bout = bout;
    gemm_one<128, 128, 5><<<dim3(79, 25), 256, 0, stream>>>(g);
  }

  write_final<<<256, 256, 0, stream>>>(h0f, h1f, out);
}

// Round 4
// 1035.438 us; speedup vs baseline: 2.9200x; 2.9200x over previous
//
#include <hip/hip_runtime.h>

#define T_ 25
#define V_ 10000
#define NWG_ 192
#define NGRP_ 8
#define GSZ_ (NWG_ / NGRP_)

typedef short bf16x8 __attribute__((ext_vector_type(8)));
typedef float f32x4 __attribute__((ext_vector_type(4)));

__device__ __forceinline__ short f2bf(float x) {
  union { float f; unsigned u; } v; v.f = x;
  unsigned r = (v.u + 0x7fffu + ((v.u >> 16) & 1u)) >> 16;
  return (short)r;
}
__device__ __forceinline__ float sigm(float z) { return 1.f / (1.f + __expf(-z)); }
__device__ __forceinline__ float tanhfast(float z) {
  float e = __expf(2.f * z);
  return 1.f - 2.f / (e + 1.f);
}

__device__ __forceinline__ void gload_lds16(const void* g, void* l) {
  __builtin_amdgcn_global_load_lds((const __attribute__((address_space(1))) void*)g,
                                   (__attribute__((address_space(3))) void*)l, 16, 0, 0);
}

// MFMA-A-fragment-linear layout: value (row, col) lives at
// blk = (col>>5)*8 + (row>>4); lane = (row&15) | (((col>>3)&3)<<4); elem = col&7
__device__ __forceinline__ int FL(int row, int col) {
  return (((col >> 5) * 8 + (row >> 4)) << 9) | (((row & 15) | (((col >> 3) & 3) << 4)) << 3) | (col & 7);
}

// ---------------- device-scope grid barrier, tree arrival + relaxed poll ----------------
// bar layout (ints): [0]=generation flag; [32 + g*32] = group-g arrival counter (g<8),
// each on its own 128B line; [32 + 8*32] = super counter.
__device__ __forceinline__ void gbar(int* bar, int gen) {
  __syncthreads();
  if (threadIdx.x == 0) {
    int* flag = &bar[0];
    int* gc   = &bar[32 + (blockIdx.x & (NGRP_ - 1)) * 32];
    int* sup  = &bar[32 + NGRP_ * 32];
    // arrival (release own writes; acquire peers' via RMW chain)
    int prev = __hip_atomic_fetch_add(gc, 1, __ATOMIC_ACQ_REL, __HIP_MEMORY_SCOPE_AGENT);
    if (prev == GSZ_ - 1) {
      __hip_atomic_store(gc, 0, __ATOMIC_RELAXED, __HIP_MEMORY_SCOPE_AGENT);
      int sp = __hip_atomic_fetch_add(sup, 1, __ATOMIC_ACQ_REL, __HIP_MEMORY_SCOPE_AGENT);
      if (sp == NGRP_ - 1) {
        __hip_atomic_store(sup, 0, __ATOMIC_RELAXED, __HIP_MEMORY_SCOPE_AGENT);
        __hip_atomic_store(flag, gen, __ATOMIC_RELEASE, __HIP_MEMORY_SCOPE_AGENT);
      }
    }
    // wait: relaxed spin (sc1 bypasses L2, no invalidate per poll); acquire only to confirm
    while (__hip_atomic_load(flag, __ATOMIC_ACQUIRE, __HIP_MEMORY_SCOPE_AGENT) < gen) {
      int it = 0;
      do {
        __builtin_amdgcn_s_sleep(8);
      } while (__hip_atomic_load(flag, __ATOMIC_RELAXED, __HIP_MEMORY_SCOPE_AGENT) < gen && ++it < 16);
    }
  }
  __syncthreads();
}

// ---------------- merged transpose + cast f32[R,C] -> bf16[C,R] ----------------
struct TJob { const float* src; short* dst; int R, C, t0; };
struct TJobs { TJob j[10]; };

__global__ void tcast_all(TJobs J) {
  __shared__ float t[32][33];
  int bid = blockIdx.x;
  int ji = 0;
  while (ji < 9 && bid >= J.j[ji + 1].t0) ji++;
  const float* src = J.j[ji].src;
  short* dst = J.j[ji].dst;
  int R = J.j[ji].R, C = J.j[ji].C;
  int rel = bid - J.j[ji].t0;
  int ctiles = (C + 31) >> 5;
  int rt0 = (rel / ctiles) * 32, ct0 = (rel % ctiles) * 32;
  int tx = threadIdx.x, ty = threadIdx.y; // 32x8
#pragma unroll
  for (int i = 0; i < 4; i++) {
    int r = rt0 + ty + i * 8, c = ct0 + tx;
    if (r < R && c < C) t[ty + i * 8][tx] = src[(size_t)r * C + c];
  }
  __syncthreads();
#pragma unroll
  for (int i = 0; i < 4; i++) {
    int c = ct0 + ty + i * 8, r = rt0 + tx;
    if (r < R && c < C) dst[(size_t)c * R + r] = f2bf(t[tx][ty + i * 8]);
  }
}

// ---------------- build X0 [T*B, 1024] bf16 : [emb(tok) | cnn] ----------------
__global__ void build_x0(const int* __restrict__ tok, const float* __restrict__ emb,
                         const float* __restrict__ cnn, short* __restrict__ X0) {
  int row = blockIdx.x;           // t*128 + b
  int t = row >> 7, b = row & 127;
  int tk = tok[b * T_ + t];
  const float* er = emb + (size_t)tk * 512;
  short* dst = X0 + (size_t)row * 1024;
  for (int i = threadIdx.x; i < 1024; i += 256)
    dst[i] = f2bf(i < 512 ? er[i] : cnn[b * 512 + (i - 512)]);
}

// ---------------- init hidden state (xh1b in FL layout) ----------------
__global__ void init_h(const float* __restrict__ ihs, float* h0f, float* h1f, short* xh1b) {
  int i = blockIdx.x * 256 + threadIdx.x;  // 0 .. 65535, i = b*512 + h
  if (i < 65536) {
    int b = i >> 9, h = i & 511;
    float v0 = ihs[i], v1 = ihs[65536 + i];
    h0f[i] = v0; h1f[i] = v1;
    xh1b[FL(b, h)] = f2bf(v0);
    xh1b[FL(b, 512 + h)] = f2bf(v1);
  }
}

__global__ void write_final(const float* __restrict__ h0f, const float* __restrict__ h1f,
                            float* __restrict__ out) {
  int i = blockIdx.x * 256 + threadIdx.x;
  if (i < 65536) {
    out[32000000 + i] = h0f[i];
    out[32000000 + 65536 + i] = h1f[i];
  }
}

// ---------------- persistent recurrence kernel ----------------
struct RP {
  short *xh1b, *rh0b, *xc1b0, *xc1b1, *H1all;
  float *u0f, *u1f, *h0f, *h1f;
  const float *A0;
  const short *Whur0T, *Whc0T, *W1urT, *Wc1T;
  const float *bu1, *br1, *bc1;
  int *bar;
};

template<int NKS>
__device__ __forceinline__ void wload(const short* __restrict__ Wt, int n0, int lane, bf16x8* wfr) {
  const short* p = Wt + (size_t)(n0 + (lane & 15)) * (NKS * 32) + ((lane >> 4) * 8);
#pragma unroll
  for (int ks = 0; ks < NKS; ks++) wfr[ks] = *(const bf16x8*)(p + (size_t)ks * 32);
}

template<int NKS>
__device__ __forceinline__ void kcompute(const short* __restrict__ A, int rb0, int lane,
                                         const bf16x8* __restrict__ wfr, f32x4* acc) {
  const short* ap = A + rb0 * 512 + lane * 8;
#pragma unroll
  for (int ks = 0; ks < NKS; ks++) {
    bf16x8 a0 = *(const bf16x8*)(ap + ks * 4096);
    bf16x8 a1 = *(const bf16x8*)(ap + ks * 4096 + 512);
    acc[ks & 1]       = __builtin_amdgcn_mfma_f32_16x16x32_bf16(a0, wfr[ks], acc[ks & 1], 0, 0, 0);
    acc[2 + (ks & 1)] = __builtin_amdgcn_mfma_f32_16x16x32_bf16(a1, wfr[ks], acc[2 + (ks & 1)], 0, 0, 0);
    if ((ks & 7) == 7) asm volatile("" ::: "memory");   // cap load-hoisting window
  }
}

__global__ __launch_bounds__(256) void recurrence(RP p) {
  const int role = blockIdx.x;
  const int tid = threadIdx.x, wv = tid >> 6, lane = tid & 63;
  const int lr = lane & 15, lg = lane >> 4;
  int gen = 0;

  if (role < 64) {
    // ---- P3: layer-1 u,r gates. out[128,1024], K=1024, A=xh1b ----
    const int nt = role >> 1, mh = role & 1;
    const int colb = nt * 32 + (wv & 1) * 16;
    const int rb0 = (mh * 64 + (wv >> 1) * 32) >> 4;
    bf16x8 wfr[32]; wload<32>(p.W1urT, colb, lane, wfr);
    gbar(p.bar, ++gen); gbar(p.bar, ++gen);
    for (int t = 0; t < T_; t++) {
      f32x4 acc[4] = {};
      kcompute<32>(p.xh1b, rb0, lane, wfr, acc);
      f32x4 am[2] = { acc[0] + acc[1], acc[2] + acc[3] };
      short* xc = (t & 1) ? p.xc1b1 : p.xc1b0;
#pragma unroll
      for (int m = 0; m < 2; m++)
#pragma unroll
        for (int i = 0; i < 4; i++) {
          int row = (rb0 + m) * 16 + lg * 4 + i;
          int col = colb + lr;
          float z = am[m][i] + (col < 512 ? p.bu1[col] : p.br1[col - 512]);
          float s = sigm(z);
          if (col < 512) p.u1f[row * 512 + col] = s;
          else xc[FL(row, col)] = f2bf(s * p.h1f[row * 512 + (col - 512)]);
        }
      gbar(p.bar, ++gen);   // end alpha(t)
      gbar(p.bar, ++gen);   // end beta(t) (idle)
    }
  } else if (role < 128) {
    // ---- P1: layer-0 u,r gates for step t+1. out[128,1024], K=512, A=xh1b[:,:512] ----
    const int r2 = role - 64;
    const int nt = r2 >> 1, mh = r2 & 1;
    const int colb = nt * 32 + (wv & 1) * 16;
    const int rb0 = (mh * 64 + (wv >> 1) * 32) >> 4;
    bf16x8 wfr[16]; wload<16>(p.Whur0T, colb, lane, wfr);
    auto doP1 = [&](int tt) {
      f32x4 acc[4] = {};
      kcompute<16>(p.xh1b, rb0, lane, wfr, acc);
      f32x4 am[2] = { acc[0] + acc[1], acc[2] + acc[3] };
      const float* a0s = p.A0 + (size_t)tt * 196608;
#pragma unroll
      for (int m = 0; m < 2; m++)
#pragma unroll
        for (int i = 0; i < 4; i++) {
          int row = (rb0 + m) * 16 + lg * 4 + i;
          int col = colb + lr;
          float z = am[m][i] + a0s[row * 1536 + col];
          float s = sigm(z);
          if (col < 512) p.u0f[row * 512 + col] = s;
          else p.rh0b[FL(row, col - 512)] = f2bf(s * p.h0f[row * 512 + (col - 512)]);
        }
    };
    doP1(0);
    gbar(p.bar, ++gen); gbar(p.bar, ++gen);
    for (int t = 0; t < T_; t++) {
      if (t < T_ - 1) doP1(t + 1);
      gbar(p.bar, ++gen);
      gbar(p.bar, ++gen);
    }
  } else if (role < 160) {
    // ---- P4: layer-1 cand + h1 update. out[128,512], K=1024, A=xc1b[t&1] ----
    const int r4 = role - 128;
    const int nt = r4 >> 1, mh = r4 & 1;
    const int colb = nt * 32 + (wv & 1) * 16;
    const int rb0 = (mh * 64 + (wv >> 1) * 32) >> 4;
    bf16x8 wfr[32]; wload<32>(p.Wc1T, colb, lane, wfr);
    gbar(p.bar, ++gen); gbar(p.bar, ++gen);
    for (int t = 0; t < T_; t++) {
      gbar(p.bar, ++gen);   // alpha idle
      const short* xc = (t & 1) ? p.xc1b1 : p.xc1b0;
      f32x4 acc[4] = {};
      kcompute<32>(xc, rb0, lane, wfr, acc);
      f32x4 am[2] = { acc[0] + acc[1], acc[2] + acc[3] };
#pragma unroll
      for (int m = 0; m < 2; m++)
#pragma unroll
        for (int i = 0; i < 4; i++) {
          int row = (rb0 + m) * 16 + lg * 4 + i;
          int col = colb + lr;
          float z = am[m][i] + p.bc1[col];
          float cc = tanhfast(z);
          float u = p.u1f[row * 512 + col], h = p.h1f[row * 512 + col];
          float hn = u * h + (1.f - u) * cc;
          p.h1f[row * 512 + col] = hn;
          short hb = f2bf(hn);
          p.xh1b[FL(row, 512 + col)] = hb;
          p.H1all[(size_t)t * 65536 + row * 512 + col] = hb;
        }
      gbar(p.bar, ++gen);   // end beta(t)
    }
  } else {
    // ---- P2: layer-0 cand + h0 update for step t+1. out[128,512], K=512, A=rh0b ----
    const int r2 = role - 160;
    const int nt = r2 >> 1, mh = r2 & 1;
    const int colb = nt * 32 + (wv & 1) * 16;
    const int rb0 = (mh * 64 + (wv >> 1) * 32) >> 4;
    bf16x8 wfr[16]; wload<16>(p.Whc0T, colb, lane, wfr);
    auto doP2 = [&](int tt) {
      f32x4 acc[4] = {};
      kcompute<16>(p.rh0b, rb0, lane, wfr, acc);
      f32x4 am[2] = { acc[0] + acc[1], acc[2] + acc[3] };
      const float* a0s = p.A0 + (size_t)tt * 196608;
      short* xc = (tt & 1) ? p.xc1b1 : p.xc1b0;
#pragma unroll
      for (int m = 0; m < 2; m++)
#pragma unroll
        for (int i = 0; i < 4; i++) {
          int row = (rb0 + m) * 16 + lg * 4 + i;
          int col = colb + lr;
          float z = am[m][i] + a0s[row * 1536 + 1024 + col];
          float c = tanhfast(z);
          float u = p.u0f[row * 512 + col], h = p.h0f[row * 512 + col];
          float hn = u * h + (1.f - u) * c;
          p.h0f[row * 512 + col] = hn;
          short hb = f2bf(hn);
          p.xh1b[FL(row, col)] = hb;
          xc[FL(row, col)] = hb;
        }
    };
    gbar(p.bar, ++gen);
    doP2(0);
    gbar(p.bar, ++gen);
    for (int t = 0; t < T_; t++) {
      gbar(p.bar, ++gen);   // alpha idle
      if (t < T_ - 1) doP2(t + 1);
      gbar(p.bar, ++gen);
    }
  }
}

// ---------------- big MFMA GEMM (A0 precompute + logits) ----------------
struct GP {
  const short* A; const short* Bt;
  int lda, ldb, N, K;
  const float* bias0; const float* bias1; const float* bias2;
  float* fdst;
  float* outp; const float* bout;
};

template<int BM, int BN, int VAR>
__device__ __forceinline__ void gemm_core(const GP& p, short* la, short* lb, int bm, int bn, short* smem) {
  const int tid = threadIdx.x;
  const int wave = tid >> 6, lane = tid & 63;
  const int wm = wave >> 1, wn = wave & 1;
  constexpr int WM = BM / 2, WN = BN / 2;
  constexpr int MF = WM / 16, NF = WN / 16;
  const int lr = lane & 15, lg = lane >> 4;
  const short* Abase = p.A + (size_t)bm * BM * p.lda;
  const short* Bbase = p.Bt + (size_t)bn * BN * p.ldb;
  const int bnmax = p.N - bn * BN;
  f32x4 acc[MF][NF] = {};
  const int nkb = p.K >> 6;

  auto stA = [&](int buf, int k0) {
    constexpr int NI = BM / 32;
#pragma unroll
    for (int j = 0; j < NI; j++) {
      int glin = j * 256 + tid;
      int row = glin >> 3, gc = glin & 7;
      int gcs = gc ^ (row & 7);
      gload_lds16(Abase + (size_t)row * p.lda + k0 + gcs * 8,
                  &la[buf * BM * 64 + j * 2048 + wave * 512]);
    }
  };
  auto stB = [&](int buf, int k0) {
    constexpr int NI = BN / 32;
#pragma unroll
    for (int j = 0; j < NI; j++) {
      int glin = j * 256 + tid;
      int row = glin >> 3, gc = glin & 7;
      int gcs = gc ^ (row & 7);
      int rc = row < bnmax ? row : bnmax - 1;
      gload_lds16(Bbase + (size_t)rc * p.ldb + k0 + gcs * 8,
                  &lb[buf * BN * 64 + j * 2048 + wave * 512]);
    }
  };

  stA(0, 0); stB(0, 0);
  __syncthreads();
  int buf = 0;
  for (int kb = 0; kb < nkb; kb++) {
    if (kb + 1 < nkb) { stA(buf ^ 1, (kb + 1) * 64); stB(buf ^ 1, (kb + 1) * 64); }
    bf16x8 af[2][MF], bfr[2][NF];
#pragma unroll
    for (int ks = 0; ks < 2; ks++) {
#pragma unroll
      for (int m = 0; m < MF; m++) {
        int ar = wm * WM + m * 16 + lr;
        af[ks][m] = *(const bf16x8*)&la[buf * BM * 64 + (ar * 8 + ((ks * 4 + lg) ^ (ar & 7))) * 8];
      }
#pragma unroll
      for (int n = 0; n < NF; n++) {
        int br = wn * WN + n * 16 + lr;
        bfr[ks][n] = *(const bf16x8*)&lb[buf * BN * 64 + (br * 8 + ((ks * 4 + lg) ^ (br & 7))) * 8];
      }
    }
#pragma unroll
    for (int ks = 0; ks < 2; ks++)
#pragma unroll
      for (int m = 0; m < MF; m++)
#pragma unroll
        for (int n = 0; n < NF; n++)
          acc[m][n] = __builtin_amdgcn_mfma_f32_16x16x32_bf16(af[ks][m], bfr[ks][n], acc[m][n], 0, 0, 0);
    __syncthreads();
    buf ^= 1;
  }

  if constexpr (VAR == 0) {            // A0 = x@Wx + bias (3 gates), f32 row-major out
#pragma unroll
    for (int m = 0; m < MF; m++)
#pragma unroll
      for (int n = 0; n < NF; n++)
#pragma unroll
        for (int i = 0; i < 4; i++) {
          int row = bm * BM + wm * WM + m * 16 + lg * 4 + i;
          int col = bn * BN + wn * WN + n * 16 + lr;
          if (col >= p.N) continue;
          float bias = col < 512 ? p.bias0[col] : (col < 1024 ? p.bias1[col - 512] : p.bias2[col - 1024]);
          p.fdst[(size_t)row * 1536 + col] = acc[m][n][i] + bias;
        }
  } else {                             // VAR 5: logits -> smem transpose -> float4 full-line stores
    float* fs = (float*)smem;          // 128x128 f32 = 64 KiB
#pragma unroll
    for (int m = 0; m < MF; m++)
#pragma unroll
      for (int n = 0; n < NF; n++)
#pragma unroll
        for (int i = 0; i < 4; i++) {
          int lrow = wm * WM + m * 16 + lg * 4 + i;
          int lcol = wn * WN + n * 16 + lr;
          int col = bn * BN + lcol;
          fs[lrow * 128 + lcol] = acc[m][n][i] + (col < p.N ? p.bout[col] : 0.f);
        }
    __syncthreads();
#pragma unroll
    for (int j = 0; j < 16; j++) {
      int idx = j * 256 + tid;         // 0..4095 float4 slots
      int r = idx >> 5, c4 = (idx & 31) << 2;
      int gr = bm * BM + r;
      int tt = gr >> 7, b = gr & 127;
      int col = bn * BN + c4;
      if (col < p.N) {
        f32x4 v = *(const f32x4*)&fs[r * 128 + c4];
        *(f32x4*)&p.outp[((size_t)b * T_ + tt) * V_ + col] = v;
      }
    }
  }
}

template<int BM, int BN, int VAR>
__global__ __launch_bounds__(256) void gemm_one(GP p) {
  __shared__ short smem[2 * BM * 64 + 2 * BN * 64];
  int bm, bn;
  if constexpr (VAR == 5) {
    int lin = blockIdx.y * gridDim.x + blockIdx.x;     // 0..1974
    const int nwg = 79 * 25, q = nwg / 8, r8 = nwg % 8;
    int xcd = lin % 8, idx = lin / 8;
    int nlin = (xcd < r8 ? xcd * (q + 1) : r8 * (q + 1) + (xcd - r8) * q) + idx;
    bm = nlin % 25; bn = nlin / 25;                    // bn-major chunks per XCD
  } else { bm = blockIdx.y; bn = blockIdx.x; }
  gemm_core<BM, BN, VAR>(p, smem, smem + 2 * BM * 64, bm, bn, smem);
}

// ---------------- host ----------------
extern "C" void kernel_launch(void* const* d_in, const int* in_sizes, int n_in,
                              void* d_out, int out_size, void* d_ws, size_t ws_size,
                              hipStream_t stream) {
  const int*   tokens = (const int*)  d_in[0];
  const float* cnn    = (const float*)d_in[1];
  const float* ihs    = (const float*)d_in[2];
  const float* emb    = (const float*)d_in[3];
  const float* Wu0 = (const float*)d_in[4];
  const float* Wr0 = (const float*)d_in[5];
  const float* Wc0 = (const float*)d_in[6];
  const float* bu0 = (const float*)d_in[7];
  const float* br0 = (const float*)d_in[8];
  const float* bc0 = (const float*)d_in[9];
  const float* Wu1 = (const float*)d_in[10];
  const float* Wr1 = (const float*)d_in[11];
  const float* Wc1 = (const float*)d_in[12];
  const float* bu1 = (const float*)d_in[13];
  const float* br1 = (const float*)d_in[14];
  const float* bc1 = (const float*)d_in[15];
  const float* Wout = (const float*)d_in[16];
  const float* bout = (const float*)d_in[17];
  float* out = (float*)d_out;

  char* w = (char*)d_ws;
  size_t off = 0;
  auto alloc = [&](size_t bytes) { void* p = w + off; off += (bytes + 255) & ~255ull; return p; };
  short* WxT    = (short*)alloc(1536 * 1024 * 2);
  short* Whur0T = (short*)alloc(1024 * 512 * 2);
  short* Whc0T  = (short*)alloc(512 * 512 * 2);
  short* W1urT  = (short*)alloc(1024 * 1024 * 2);
  short* Wc1T   = (short*)alloc(512 * 1024 * 2);
  short* WoutT  = (short*)alloc((size_t)10000 * 512 * 2);
  short* X0     = (short*)alloc((size_t)3200 * 1024 * 2);
  float* A0     = (float*)alloc((size_t)3200 * 1536 * 4);
  short* H1all  = (short*)alloc((size_t)3200 * 512 * 2);
  float* u0f    = (float*)alloc(128 * 512 * 4);
  float* u1f    = (float*)alloc(128 * 512 * 4);
  float* h0f    = (float*)alloc(128 * 512 * 4);
  float* h1f    = (float*)alloc(128 * 512 * 4);
  short* rh0b   = (short*)alloc(128 * 512 * 2);
  short* xh1b   = (short*)alloc(128 * 1024 * 2);
  short* xc1b0  = (short*)alloc(128 * 1024 * 2);
  short* xc1b1  = (short*)alloc(128 * 1024 * 2);
  int*   bar    = (int*)alloc(4096);
  (void)ws_size; (void)in_sizes; (void)n_in; (void)out_size;

  {
    TJobs J;
    J.j[0] = { Wu0,              WxT,                1024, 512,  0    };
    J.j[1] = { Wr0,              WxT + 512 * 1024,   1024, 512,  512  };
    J.j[2] = { Wc0,              WxT + 1024 * 1024,  1024, 512,  1024 };
    J.j[3] = { Wu0 + 1024 * 512, Whur0T,             512,  512,  1536 };
    J.j[4] = { Wr0 + 1024 * 512, Whur0T + 512 * 512, 512,  512,  1792 };
    J.j[5] = { Wc0 + 1024 * 512, Whc0T,              512,  512,  2048 };
    J.j[6] = { Wu1,              W1urT,              1024, 512,  2304 };
    J.j[7] = { Wr1,              W1urT + 512 * 1024, 1024, 512,  2816 };
    J.j[8] = { Wc1,              Wc1T,               1024, 512,  3328 };
    J.j[9] = { Wout,             WoutT,              512,  10000, 3840 };
    tcast_all<<<8848, dim3(32, 8), 0, stream>>>(J);
  }

  build_x0<<<3200, 256, 0, stream>>>(tokens, emb, cnn, X0);
  init_h<<<256, 256, 0, stream>>>(ihs, h0f, h1f, xh1b);
  hipMemsetAsync(bar, 0, 4096, stream);

  // A0 = X0 @ WxT^T + biases : [3200,1536] f32
  {
    GP g = {};
    g.A = X0; g.lda = 1024; g.Bt = WxT; g.ldb = 1024; g.N = 1536; g.K = 1024;
    g.bias0 = bu0; g.bias1 = br0; g.bias2 = bc0; g.fdst = A0;
    gemm_one<128, 128, 0><<<dim3(12, 25), 256, 0, stream>>>(g);
  }

  // persistent recurrence: 52 barrier-phases, weights in registers
  {
    RP r = {};
    r.xh1b = xh1b; r.rh0b = rh0b; r.xc1b0 = xc1b0; r.xc1b1 = xc1b1; r.H1all = H1all;
    r.u0f = u0f; r.u1f = u1f; r.h0f = h0f; r.h1f = h1f;
    r.A0 = A0;
    r.Whur0T = Whur0T; r.Whc0T = Whc0T; r.W1urT = W1urT; r.Wc1T = Wc1T;
    r.bu1 = bu1; r.br1 = br1; r.bc1 = bc1;
    r.bar = bar;
    recurrence<<<dim3(NWG_), 256, 0, stream>>>(r);
  }

  // logits = H1all @ WoutT^T + bout -> out[b,t,v]
  {
    GP g = {};
    g.A = H1all; g.lda = 512; g.Bt = WoutT; g.ldb = 512; g.N = 10000; g.K = 512;
    g.outp = out; g.bout = bout;
    gemm_one<128, 128, 5><<<dim3(79, 25), 256, 0, stream>>>(g);
  }

  write_final<<<256, 256, 0, stream>>>(h0f, h1f, out);
}

// Round 5
// 532.598 us; speedup vs baseline: 5.6769x; 1.9441x over previous
//
#include <hip/hip_runtime.h>

#define T_ 25
#define V_ 10000
#define NWG_ 192
#define NGRP_ 8
#define GSZ_ (NWG_ / NGRP_)

typedef short bf16x8 __attribute__((ext_vector_type(8)));
typedef float f32x4 __attribute__((ext_vector_type(4)));

__device__ __forceinline__ short f2bf(float x) {
  union { float f; unsigned u; } v; v.f = x;
  unsigned r = (v.u + 0x7fffu + ((v.u >> 16) & 1u)) >> 16;
  return (short)r;
}
__device__ __forceinline__ float sigm(float z) { return 1.f / (1.f + __expf(-z)); }
__device__ __forceinline__ float tanhfast(float z) {
  float e = __expf(2.f * z);
  return 1.f - 2.f / (e + 1.f);
}

__device__ __forceinline__ void gload_lds16(const void* g, void* l) {
  __builtin_amdgcn_global_load_lds((const __attribute__((address_space(1))) void*)g,
                                   (__attribute__((address_space(3))) void*)l, 16, 0, 0);
}

// ---- coherent-bypass (sc0 sc1) memory ops: go to coherence point, no L2 cache ops ----
__device__ __forceinline__ void vwait0() { asm volatile("s_waitcnt vmcnt(0)" ::: "memory"); }
__device__ __forceinline__ void cload16(bf16x8* d, const short* p) {
  asm volatile("global_load_dwordx4 %0, %1, off sc0 sc1" : "=v"(*d) : "v"(p) : "memory");
}
__device__ __forceinline__ void cloadf(float* d, const float* p) {
  asm volatile("global_load_dword %0, %1, off sc0 sc1" : "=v"(*d) : "v"(p) : "memory");
}
__device__ __forceinline__ void cstoref(float* p, float v) {
  asm volatile("global_store_dword %0, %1, off sc0 sc1" :: "v"(p), "v"(v) : "memory");
}
__device__ __forceinline__ void cstores(short* p, int v) {
  asm volatile("global_store_short %0, %1, off sc0 sc1" :: "v"(p), "v"(v) : "memory");
}

// MFMA-A-fragment-linear layout: value (row, col) lives at
// blk = (col>>5)*8 + (row>>4); lane = (row&15) | (((col>>3)&3)<<4); elem = col&7
__device__ __forceinline__ int FL(int row, int col) {
  return (((col >> 5) * 8 + (row >> 4)) << 9) | (((row & 15) | (((col >> 3) & 3) << 4)) << 3) | (col & 7);
}

// ---------------- grid barrier: relaxed atomics only, monotone counters ----------------
// bar ints: flag[g] at [g*32] (g<8); group counters at [256 + g*32]; super at [512].
__device__ __forceinline__ void gbar(int* bar, int gen) {
  vwait0();                       // every wave drains its coherent loads/stores
  __syncthreads();
  if (threadIdx.x == 0) {
    const int g = blockIdx.x & (NGRP_ - 1);
    int prev = __hip_atomic_fetch_add(&bar[256 + g * 32], 1, __ATOMIC_RELAXED, __HIP_MEMORY_SCOPE_AGENT);
    if (prev == gen * GSZ_ - 1) {
      int sp = __hip_atomic_fetch_add(&bar[512], 1, __ATOMIC_RELAXED, __HIP_MEMORY_SCOPE_AGENT);
      if (sp == gen * NGRP_ - 1) {
#pragma unroll
        for (int i = 0; i < NGRP_; i++)
          __hip_atomic_store(&bar[i * 32], gen, __ATOMIC_RELAXED, __HIP_MEMORY_SCOPE_AGENT);
      }
    }
    while (__hip_atomic_load(&bar[g * 32], __ATOMIC_RELAXED, __HIP_MEMORY_SCOPE_AGENT) < gen)
      __builtin_amdgcn_s_sleep(1);
  }
  __syncthreads();
}

// ---------------- merged transpose + cast f32[R,C] -> bf16[C,R] ----------------
struct TJob { const float* src; short* dst; int R, C, t0; };
struct TJobs { TJob j[10]; };

__global__ void tcast_all(TJobs J) {
  __shared__ float t[32][33];
  int bid = blockIdx.x;
  int ji = 0;
  while (ji < 9 && bid >= J.j[ji + 1].t0) ji++;
  const float* src = J.j[ji].src;
  short* dst = J.j[ji].dst;
  int R = J.j[ji].R, C = J.j[ji].C;
  int rel = bid - J.j[ji].t0;
  int ctiles = (C + 31) >> 5;
  int rt0 = (rel / ctiles) * 32, ct0 = (rel % ctiles) * 32;
  int tx = threadIdx.x, ty = threadIdx.y; // 32x8
#pragma unroll
  for (int i = 0; i < 4; i++) {
    int r = rt0 + ty + i * 8, c = ct0 + tx;
    if (r < R && c < C) t[ty + i * 8][tx] = src[(size_t)r * C + c];
  }
  __syncthreads();
#pragma unroll
  for (int i = 0; i < 4; i++) {
    int c = ct0 + ty + i * 8, r = rt0 + tx;
    if (r < R && c < C) dst[(size_t)c * R + r] = f2bf(t[tx][ty + i * 8]);
  }
}

// ---------------- build X0 [T*B, 1024] bf16 : [emb(tok) | cnn] ----------------
__global__ void build_x0(const int* __restrict__ tok, const float* __restrict__ emb,
                         const float* __restrict__ cnn, short* __restrict__ X0) {
  int row = blockIdx.x;           // t*128 + b
  int t = row >> 7, b = row & 127;
  int tk = tok[b * T_ + t];
  const float* er = emb + (size_t)tk * 512;
  short* dst = X0 + (size_t)row * 1024;
  for (int i = threadIdx.x; i < 1024; i += 256)
    dst[i] = f2bf(i < 512 ? er[i] : cnn[b * 512 + (i - 512)]);
}

// ---------------- init hidden state (xh1b in FL layout) ----------------
__global__ void init_h(const float* __restrict__ ihs, float* h0f, float* h1f, short* xh1b) {
  int i = blockIdx.x * 256 + threadIdx.x;  // 0 .. 65535, i = b*512 + h
  if (i < 65536) {
    int b = i >> 9, h = i & 511;
    float v0 = ihs[i], v1 = ihs[65536 + i];
    h0f[i] = v0; h1f[i] = v1;
    xh1b[FL(b, h)] = f2bf(v0);
    xh1b[FL(b, 512 + h)] = f2bf(v1);
  }
}

__global__ void write_final(const float* __restrict__ h0f, const float* __restrict__ h1f,
                            float* __restrict__ out) {
  int i = blockIdx.x * 256 + threadIdx.x;
  if (i < 65536) {
    out[32000000 + i] = h0f[i];
    out[32000000 + 65536 + i] = h1f[i];
  }
}

// ---------------- persistent recurrence kernel ----------------
struct RP {
  short *xh1b, *rh0b, *xc1b0, *xc1b1, *H1all;
  float *u0f, *u1f, *h0f, *h1f;
  const float *A0;
  const short *Whur0T, *Whc0T, *W1urT, *Wc1T;
  const float *bu1, *br1, *bc1;
  int *bar;
};

template<int NKS>
__device__ __forceinline__ void wload(const short* __restrict__ Wt, int n0, int lane, bf16x8* wfr) {
  const short* p = Wt + (size_t)(n0 + (lane & 15)) * (NKS * 32) + ((lane >> 4) * 8);
#pragma unroll
  for (int ks = 0; ks < NKS; ks++) wfr[ks] = *(const bf16x8*)(p + (size_t)ks * 32);
}

// A-read via coherent loads, 2-deep counted-vmcnt pipeline (chunk = 4 k-slices = 8 loads).
// vmcnt(8): chunk c is oldest and >=8 newer ops are in flight -> always fully drains chunk c.
template<int NKS>
__device__ __forceinline__ void kcompute_coh(const short* __restrict__ A, int rb0, int lane,
                                             const bf16x8* __restrict__ wfr, f32x4* acc) {
  const short* ap = A + rb0 * 512 + lane * 8;
  constexpr int NCH = NKS / 4;
  bf16x8 s0[2][4], s1[2][4];
#pragma unroll
  for (int j = 0; j < 4; j++) {
    cload16(&s0[0][j], ap + j * 4096);
    cload16(&s1[0][j], ap + j * 4096 + 512);
  }
#pragma unroll
  for (int c = 0; c < NCH; c++) {
    const int cb = c & 1;
    if (c + 1 < NCH) {
#pragma unroll
      for (int j = 0; j < 4; j++) {
        int ks = (c + 1) * 4 + j;
        cload16(&s0[cb ^ 1][j], ap + ks * 4096);
        cload16(&s1[cb ^ 1][j], ap + ks * 4096 + 512);
      }
      asm volatile("s_waitcnt vmcnt(8)" ::: "memory");
    } else {
      asm volatile("s_waitcnt vmcnt(0)" ::: "memory");
    }
    __builtin_amdgcn_sched_barrier(0);
#pragma unroll
    for (int j = 0; j < 4; j++) {
      int ks = c * 4 + j;
      acc[ks & 1]       = __builtin_amdgcn_mfma_f32_16x16x32_bf16(s0[cb][j], wfr[ks], acc[ks & 1], 0, 0, 0);
      acc[2 + (ks & 1)] = __builtin_amdgcn_mfma_f32_16x16x32_bf16(s1[cb][j], wfr[ks], acc[2 + (ks & 1)], 0, 0, 0);
    }
  }
}

__global__ __launch_bounds__(256) void recurrence(RP p) {
  const int role = blockIdx.x;
  const int tid = threadIdx.x, wv = tid >> 6, lane = tid & 63;
  const int lr = lane & 15, lg = lane >> 4;
  int gen = 0;

  if (role < 64) {
    // ---- P3: layer-1 u,r gates. out[128,1024], K=1024, A=xh1b ----
    const int nt = role >> 1, mh = role & 1;
    const int colb = nt * 32 + (wv & 1) * 16;
    const int rb0 = mh * 4 + (wv >> 1) * 2;
    const int col = colb + lr;
    bf16x8 wfr[32]; wload<32>(p.W1urT, colb, lane, wfr);
    gbar(p.bar, ++gen); gbar(p.bar, ++gen);
    for (int t = 0; t < T_; t++) {
      f32x4 acc[4] = {};
      kcompute_coh<32>(p.xh1b, rb0, lane, wfr, acc);
      f32x4 am[2] = { acc[0] + acc[1], acc[2] + acc[3] };
      short* xc = (t & 1) ? p.xc1b1 : p.xc1b0;
      if (colb < 512) {
#pragma unroll
        for (int m = 0; m < 2; m++)
#pragma unroll
          for (int i = 0; i < 4; i++) {
            int row = (rb0 + m) * 16 + lg * 4 + i;
            cstoref(&p.u1f[row * 512 + col], sigm(am[m][i] + p.bu1[col]));
          }
      } else {
        float hv[8];
#pragma unroll
        for (int m = 0; m < 2; m++)
#pragma unroll
          for (int i = 0; i < 4; i++)
            cloadf(&hv[m * 4 + i], &p.h1f[((rb0 + m) * 16 + lg * 4 + i) * 512 + (col - 512)]);
        vwait0(); __builtin_amdgcn_sched_barrier(0);
#pragma unroll
        for (int m = 0; m < 2; m++)
#pragma unroll
          for (int i = 0; i < 4; i++) {
            int row = (rb0 + m) * 16 + lg * 4 + i;
            float s = sigm(am[m][i] + p.br1[col - 512]);
            cstores(&xc[FL(row, col)], f2bf(s * hv[m * 4 + i]));
          }
      }
      gbar(p.bar, ++gen);   // end alpha(t)
      gbar(p.bar, ++gen);   // end beta(t) (idle)
    }
  } else if (role < 128) {
    // ---- P1: layer-0 u,r gates for step t+1. out[128,1024], K=512, A=xh1b[:,:512] ----
    const int r2 = role - 64;
    const int nt = r2 >> 1, mh = r2 & 1;
    const int colb = nt * 32 + (wv & 1) * 16;
    const int rb0 = mh * 4 + (wv >> 1) * 2;
    const int col = colb + lr;
    bf16x8 wfr[16]; wload<16>(p.Whur0T, colb, lane, wfr);
    auto doP1 = [&](int tt) {
      f32x4 acc[4] = {};
      kcompute_coh<16>(p.xh1b, rb0, lane, wfr, acc);
      f32x4 am[2] = { acc[0] + acc[1], acc[2] + acc[3] };
      const float* a0s = p.A0 + (size_t)tt * 196608;
      if (colb < 512) {
#pragma unroll
        for (int m = 0; m < 2; m++)
#pragma unroll
          for (int i = 0; i < 4; i++) {
            int row = (rb0 + m) * 16 + lg * 4 + i;
            cstoref(&p.u0f[row * 512 + col], sigm(am[m][i] + a0s[row * 1536 + col]));
          }
      } else {
        float hv[8];
#pragma unroll
        for (int m = 0; m < 2; m++)
#pragma unroll
          for (int i = 0; i < 4; i++)
            cloadf(&hv[m * 4 + i], &p.h0f[((rb0 + m) * 16 + lg * 4 + i) * 512 + (col - 512)]);
        vwait0(); __builtin_amdgcn_sched_barrier(0);
#pragma unroll
        for (int m = 0; m < 2; m++)
#pragma unroll
          for (int i = 0; i < 4; i++) {
            int row = (rb0 + m) * 16 + lg * 4 + i;
            float s = sigm(am[m][i] + a0s[row * 1536 + col]);
            cstores(&p.rh0b[FL(row, col - 512)], f2bf(s * hv[m * 4 + i]));
          }
      }
    };
    doP1(0);
    gbar(p.bar, ++gen); gbar(p.bar, ++gen);
    for (int t = 0; t < T_; t++) {
      if (t < T_ - 1) doP1(t + 1);
      gbar(p.bar, ++gen);
      gbar(p.bar, ++gen);
    }
  } else if (role < 160) {
    // ---- P4: layer-1 cand + h1 update. out[128,512], K=1024, A=xc1b[t&1] ----
    const int r4 = role - 128;
    const int nt = r4 >> 1, mh = r4 & 1;
    const int colb = nt * 32 + (wv & 1) * 16;
    const int rb0 = mh * 4 + (wv >> 1) * 2;
    const int col = colb + lr;
    bf16x8 wfr[32]; wload<32>(p.Wc1T, colb, lane, wfr);
    gbar(p.bar, ++gen); gbar(p.bar, ++gen);
    for (int t = 0; t < T_; t++) {
      gbar(p.bar, ++gen);   // alpha idle
      const short* xc = (t & 1) ? p.xc1b1 : p.xc1b0;
      f32x4 acc[4] = {};
      kcompute_coh<32>(xc, rb0, lane, wfr, acc);
      f32x4 am[2] = { acc[0] + acc[1], acc[2] + acc[3] };
      float uv[8], hv[8];
#pragma unroll
      for (int m = 0; m < 2; m++)
#pragma unroll
        for (int i = 0; i < 4; i++) {
          int row = (rb0 + m) * 16 + lg * 4 + i;
          cloadf(&uv[m * 4 + i], &p.u1f[row * 512 + col]);
          cloadf(&hv[m * 4 + i], &p.h1f[row * 512 + col]);
        }
      vwait0(); __builtin_amdgcn_sched_barrier(0);
#pragma unroll
      for (int m = 0; m < 2; m++)
#pragma unroll
        for (int i = 0; i < 4; i++) {
          int row = (rb0 + m) * 16 + lg * 4 + i;
          float cc = tanhfast(am[m][i] + p.bc1[col]);
          float u = uv[m * 4 + i], h = hv[m * 4 + i];
          float hn = u * h + (1.f - u) * cc;
          cstoref(&p.h1f[row * 512 + col], hn);
          short hb = f2bf(hn);
          cstores(&p.xh1b[FL(row, 512 + col)], hb);
          p.H1all[(size_t)t * 65536 + row * 512 + col] = hb;   // read by next kernel only
        }
      gbar(p.bar, ++gen);   // end beta(t)
    }
  } else {
    // ---- P2: layer-0 cand + h0 update for step t+1. out[128,512], K=512, A=rh0b ----
    const int r2 = role - 160;
    const int nt = r2 >> 1, mh = r2 & 1;
    const int colb = nt * 32 + (wv & 1) * 16;
    const int rb0 = mh * 4 + (wv >> 1) * 2;
    const int col = colb + lr;
    bf16x8 wfr[16]; wload<16>(p.Whc0T, colb, lane, wfr);
    auto doP2 = [&](int tt) {
      f32x4 acc[4] = {};
      kcompute_coh<16>(p.rh0b, rb0, lane, wfr, acc);
      f32x4 am[2] = { acc[0] + acc[1], acc[2] + acc[3] };
      const float* a0s = p.A0 + (size_t)tt * 196608;
      short* xcw = (tt & 1) ? p.xc1b1 : p.xc1b0;
      float uv[8], hv[8];
#pragma unroll
      for (int m = 0; m < 2; m++)
#pragma unroll
        for (int i = 0; i < 4; i++) {
          int row = (rb0 + m) * 16 + lg * 4 + i;
          cloadf(&uv[m * 4 + i], &p.u0f[row * 512 + col]);
          cloadf(&hv[m * 4 + i], &p.h0f[row * 512 + col]);
        }
      vwait0(); __builtin_amdgcn_sched_barrier(0);
#pragma unroll
      for (int m = 0; m < 2; m++)
#pragma unroll
        for (int i = 0; i < 4; i++) {
          int row = (rb0 + m) * 16 + lg * 4 + i;
          float c = tanhfast(am[m][i] + a0s[row * 1536 + 1024 + col]);
          float u = uv[m * 4 + i], h = hv[m * 4 + i];
          float hn = u * h + (1.f - u) * c;
          cstoref(&p.h0f[row * 512 + col], hn);
          short hb = f2bf(hn);
          cstores(&p.xh1b[FL(row, col)], hb);
          cstores(&xcw[FL(row, col)], hb);
        }
    };
    gbar(p.bar, ++gen);
    doP2(0);
    gbar(p.bar, ++gen);
    for (int t = 0; t < T_; t++) {
      gbar(p.bar, ++gen);   // alpha idle
      if (t < T_ - 1) doP2(t + 1);
      gbar(p.bar, ++gen);
    }
  }
}

// ---------------- big MFMA GEMM (A0 precompute + logits) ----------------
struct GP {
  const short* A; const short* Bt;
  int lda, ldb, N, K;
  const float* bias0; const float* bias1; const float* bias2;
  float* fdst;
  float* outp; const float* bout;
};

template<int BM, int BN, int VAR>
__device__ __forceinline__ void gemm_core(const GP& p, short* la, short* lb, int bm, int bn, short* smem) {
  const int tid = threadIdx.x;
  const int wave = tid >> 6, lane = tid & 63;
  const int wm = wave >> 1, wn = wave & 1;
  constexpr int WM = BM / 2, WN = BN / 2;
  constexpr int MF = WM / 16, NF = WN / 16;
  const int lr = lane & 15, lg = lane >> 4;
  const short* Abase = p.A + (size_t)bm * BM * p.lda;
  const short* Bbase = p.Bt + (size_t)bn * BN * p.ldb;
  const int bnmax = p.N - bn * BN;
  f32x4 acc[MF][NF] = {};
  const int nkb = p.K >> 6;

  auto stA = [&](int buf, int k0) {
    constexpr int NI = BM / 32;
#pragma unroll
    for (int j = 0; j < NI; j++) {
      int glin = j * 256 + tid;
      int row = glin >> 3, gc = glin & 7;
      int gcs = gc ^ (row & 7);
      gload_lds16(Abase + (size_t)row * p.lda + k0 + gcs * 8,
                  &la[buf * BM * 64 + j * 2048 + wave * 512]);
    }
  };
  auto stB = [&](int buf, int k0) {
    constexpr int NI = BN / 32;
#pragma unroll
    for (int j = 0; j < NI; j++) {
      int glin = j * 256 + tid;
      int row = glin >> 3, gc = glin & 7;
      int gcs = gc ^ (row & 7);
      int rc = row < bnmax ? row : bnmax - 1;
      gload_lds16(Bbase + (size_t)rc * p.ldb + k0 + gcs * 8,
                  &lb[buf * BN * 64 + j * 2048 + wave * 512]);
    }
  };

  stA(0, 0); stB(0, 0);
  __syncthreads();
  int buf = 0;
  for (int kb = 0; kb < nkb; kb++) {
    if (kb + 1 < nkb) { stA(buf ^ 1, (kb + 1) * 64); stB(buf ^ 1, (kb + 1) * 64); }
    bf16x8 af[2][MF], bfr[2][NF];
#pragma unroll
    for (int ks = 0; ks < 2; ks++) {
#pragma unroll
      for (int m = 0; m < MF; m++) {
        int ar = wm * WM + m * 16 + lr;
        af[ks][m] = *(const bf16x8*)&la[buf * BM * 64 + (ar * 8 + ((ks * 4 + lg) ^ (ar & 7))) * 8];
      }
#pragma unroll
      for (int n = 0; n < NF; n++) {
        int br = wn * WN + n * 16 + lr;
        bfr[ks][n] = *(const bf16x8*)&lb[buf * BN * 64 + (br * 8 + ((ks * 4 + lg) ^ (br & 7))) * 8];
      }
    }
#pragma unroll
    for (int ks = 0; ks < 2; ks++)
#pragma unroll
      for (int m = 0; m < MF; m++)
#pragma unroll
        for (int n = 0; n < NF; n++)
          acc[m][n] = __builtin_amdgcn_mfma_f32_16x16x32_bf16(af[ks][m], bfr[ks][n], acc[m][n], 0, 0, 0);
    __syncthreads();
    buf ^= 1;
  }

  if constexpr (VAR == 0) {            // A0 = x@Wx + bias (3 gates), f32 row-major out
#pragma unroll
    for (int m = 0; m < MF; m++)
#pragma unroll
      for (int n = 0; n < NF; n++)
#pragma unroll
        for (int i = 0; i < 4; i++) {
          int row = bm * BM + wm * WM + m * 16 + lg * 4 + i;
          int col = bn * BN + wn * WN + n * 16 + lr;
          if (col >= p.N) continue;
          float bias = col < 512 ? p.bias0[col] : (col < 1024 ? p.bias1[col - 512] : p.bias2[col - 1024]);
          p.fdst[(size_t)row * 1536 + col] = acc[m][n][i] + bias;
        }
  } else {                             // VAR 5: logits -> smem transpose -> float4 full-line stores
    float* fs = (float*)smem;          // 128x128 f32 = 64 KiB
#pragma unroll
    for (int m = 0; m < MF; m++)
#pragma unroll
      for (int n = 0; n < NF; n++)
#pragma unroll
        for (int i = 0; i < 4; i++) {
          int lrow = wm * WM + m * 16 + lg * 4 + i;
          int lcol = wn * WN + n * 16 + lr;
          int col = bn * BN + lcol;
          fs[lrow * 128 + lcol] = acc[m][n][i] + (col < p.N ? p.bout[col] : 0.f);
        }
    __syncthreads();
#pragma unroll
    for (int j = 0; j < 16; j++) {
      int idx = j * 256 + tid;         // 0..4095 float4 slots
      int r = idx >> 5, c4 = (idx & 31) << 2;
      int gr = bm * BM + r;
      int tt = gr >> 7, b = gr & 127;
      int col = bn * BN + c4;
      if (col < p.N) {
        f32x4 v = *(const f32x4*)&fs[r * 128 + c4];
        *(f32x4*)&p.outp[((size_t)b * T_ + tt) * V_ + col] = v;
      }
    }
  }
}

template<int BM, int BN, int VAR>
__global__ __launch_bounds__(256) void gemm_one(GP p) {
  __shared__ short smem[2 * BM * 64 + 2 * BN * 64];
  int bm, bn;
  if constexpr (VAR == 5) {
    int lin = blockIdx.y * gridDim.x + blockIdx.x;     // 0..1974
    const int nwg = 79 * 25, q = nwg / 8, r8 = nwg % 8;
    int xcd = lin % 8, idx = lin / 8;
    int nlin = (xcd < r8 ? xcd * (q + 1) : r8 * (q + 1) + (xcd - r8) * q) + idx;
    bm = nlin % 25; bn = nlin / 25;                    // bn-major chunks per XCD
  } else { bm = blockIdx.y; bn = blockIdx.x; }
  gemm_core<BM, BN, VAR>(p, smem, smem + 2 * BM * 64, bm, bn, smem);
}

// ---------------- host ----------------
extern "C" void kernel_launch(void* const* d_in, const int* in_sizes, int n_in,
                              void* d_out, int out_size, void* d_ws, size_t ws_size,
                              hipStream_t stream) {
  const int*   tokens = (const int*)  d_in[0];
  const float* cnn    = (const float*)d_in[1];
  const float* ihs    = (const float*)d_in[2];
  const float* emb    = (const float*)d_in[3];
  const float* Wu0 = (const float*)d_in[4];
  const float* Wr0 = (const float*)d_in[5];
  const float* Wc0 = (const float*)d_in[6];
  const float* bu0 = (const float*)d_in[7];
  const float* br0 = (const float*)d_in[8];
  const float* bc0 = (const float*)d_in[9];
  const float* Wu1 = (const float*)d_in[10];
  const float* Wr1 = (const float*)d_in[11];
  const float* Wc1 = (const float*)d_in[12];
  const float* bu1 = (const float*)d_in[13];
  const float* br1 = (const float*)d_in[14];
  const float* bc1 = (const float*)d_in[15];
  const float* Wout = (const float*)d_in[16];
  const float* bout = (const float*)d_in[17];
  float* out = (float*)d_out;

  char* w = (char*)d_ws;
  size_t off = 0;
  auto alloc = [&](size_t bytes) { void* p = w + off; off += (bytes + 255) & ~255ull; return p; };
  short* WxT    = (short*)alloc(1536 * 1024 * 2);
  short* Whur0T = (short*)alloc(1024 * 512 * 2);
  short* Whc0T  = (short*)alloc(512 * 512 * 2);
  short* W1urT  = (short*)alloc(1024 * 1024 * 2);
  short* Wc1T   = (short*)alloc(512 * 1024 * 2);
  short* WoutT  = (short*)alloc((size_t)10000 * 512 * 2);
  short* X0     = (short*)alloc((size_t)3200 * 1024 * 2);
  float* A0     = (float*)alloc((size_t)3200 * 1536 * 4);
  short* H1all  = (short*)alloc((size_t)3200 * 512 * 2);
  float* u0f    = (float*)alloc(128 * 512 * 4);
  float* u1f    = (float*)alloc(128 * 512 * 4);
  float* h0f    = (float*)alloc(128 * 512 * 4);
  float* h1f    = (float*)alloc(128 * 512 * 4);
  short* rh0b   = (short*)alloc(128 * 512 * 2);
  short* xh1b   = (short*)alloc(128 * 1024 * 2);
  short* xc1b0  = (short*)alloc(128 * 1024 * 2);
  short* xc1b1  = (short*)alloc(128 * 1024 * 2);
  int*   bar    = (int*)alloc(4096);
  (void)ws_size; (void)in_sizes; (void)n_in; (void)out_size;

  {
    TJobs J;
    J.j[0] = { Wu0,              WxT,                1024, 512,  0    };
    J.j[1] = { Wr0,              WxT + 512 * 1024,   1024, 512,  512  };
    J.j[2] = { Wc0,              WxT + 1024 * 1024,  1024, 512,  1024 };
    J.j[3] = { Wu0 + 1024 * 512, Whur0T,             512,  512,  1536 };
    J.j[4] = { Wr0 + 1024 * 512, Whur0T + 512 * 512, 512,  512,  1792 };
    J.j[5] = { Wc0 + 1024 * 512, Whc0T,              512,  512,  2048 };
    J.j[6] = { Wu1,              W1urT,              1024, 512,  2304 };
    J.j[7] = { Wr1,              W1urT + 512 * 1024, 1024, 512,  2816 };
    J.j[8] = { Wc1,              Wc1T,               1024, 512,  3328 };
    J.j[9] = { Wout,             WoutT,              512,  10000, 3840 };
    tcast_all<<<8848, dim3(32, 8), 0, stream>>>(J);
  }

  build_x0<<<3200, 256, 0, stream>>>(tokens, emb, cnn, X0);
  init_h<<<256, 256, 0, stream>>>(ihs, h0f, h1f, xh1b);
  hipMemsetAsync(bar, 0, 4096, stream);   // must re-zero every call: counters are monotone

  // A0 = X0 @ WxT^T + biases : [3200,1536] f32
  {
    GP g = {};
    g.A = X0; g.lda = 1024; g.Bt = WxT; g.ldb = 1024; g.N = 1536; g.K = 1024;
    g.bias0 = bu0; g.bias1 = br0; g.bias2 = bc0; g.fdst = A0;
    gemm_one<128, 128, 0><<<dim3(12, 25), 256, 0, stream>>>(g);
  }

  // persistent recurrence: 52 barrier-phases, weights in registers
  {
    RP r = {};
    r.xh1b = xh1b; r.rh0b = rh0b; r.xc1b0 = xc1b0; r.xc1b1 = xc1b1; r.H1all = H1all;
    r.u0f = u0f; r.u1f = u1f; r.h0f = h0f; r.h1f = h1f;
    r.A0 = A0;
    r.Whur0T = Whur0T; r.Whc0T = Whc0T; r.W1urT = W1urT; r.Wc1T = Wc1T;
    r.bu1 = bu1; r.br1 = br1; r.bc1 = bc1;
    r.bar = bar;
    recurrence<<<dim3(NWG_), 256, 0, stream>>>(r);
  }

  // logits = H1all @ WoutT^T + bout -> out[b,t,v]
  {
    GP g = {};
    g.A = H1all; g.lda = 512; g.Bt = WoutT; g.ldb = 512; g.N = 10000; g.K = 512;
    g.outp = out; g.bout = bout;
    gemm_one<128, 128, 5><<<dim3(79, 25), 256, 0, stream>>>(g);
  }

  write_final<<<256, 256, 0, stream>>>(h0f, h1f, out);
}